// Round 5
// baseline (2523.261 us; speedup 1.0000x reference)
//
#include <hip/hip_runtime.h>
#include <stdint.h>

#define N_ROWS 32768
#define N_E    4096
#define E_DIM  256

typedef __attribute__((ext_vector_type(8))) short short8;
typedef __attribute__((ext_vector_type(4))) float f32x4;

// sortable-uint encoding for float max-compare
__device__ __forceinline__ unsigned int f2sort(float s) {
    unsigned int b = __float_as_uint(s);
    return (b & 0x80000000u) ? ~b : (b | 0x80000000u);
}
__device__ __forceinline__ float sort2f(unsigned int u) {
    unsigned int b = (u & 0x80000000u) ? (u ^ 0x80000000u) : ~u;
    return __uint_as_float(b);
}
__device__ __forceinline__ float keyval(unsigned long long k) {
    return sort2f((unsigned int)(k >> 32));
}
__device__ __forceinline__ unsigned short bfr(float x) {   // f32 -> bf16 RNE
    unsigned int u = __float_as_uint(x);
    return (unsigned short)((u + 0x7fffu + ((u >> 16) & 1u)) >> 16);
}
__device__ __forceinline__ float bf2f(unsigned short h) {
    return __uint_as_float((unsigned int)h << 16);
}

// ---------- kernel 1: f32 row norms (f64 accumulate, cast to f32) ----------
__global__ __launch_bounds__(256) void k_rownorm(const float* __restrict__ src,
                                                 float* __restrict__ outf) {
    int j = blockIdx.x * 4 + (threadIdx.x >> 6);
    int lane = threadIdx.x & 63;
    const float4* e4 = (const float4*)(src + (size_t)j * E_DIM);
    float4 v = e4[lane];
    double s = (double)v.x * v.x + (double)v.y * v.y + (double)v.z * v.z + (double)v.w * v.w;
    #pragma unroll
    for (int off = 1; off < 64; off <<= 1) s += __shfl_xor(s, off);
    if (lane == 0) outf[j] = (float)s;
}

// ---------- kernel 2: split emb into bf16 hi/lo ----------
__global__ __launch_bounds__(256) void k_embsplit(const float* __restrict__ emb,
                                                  unsigned short* __restrict__ ehi,
                                                  unsigned short* __restrict__ elo) {
    int g = blockIdx.x * 256 + threadIdx.x;          // float4 index
    float4 v = *(const float4*)(emb + (size_t)g * 4);
    ushort4 h, l;
    h.x = bfr(v.x); l.x = bfr(v.x - bf2f(h.x));
    h.y = bfr(v.y); l.y = bfr(v.y - bf2f(h.y));
    h.z = bfr(v.z); l.z = bfr(v.z - bf2f(h.z));
    h.w = bfr(v.w); l.w = bfr(v.w - bf2f(h.w));
    *(ushort4*)(ehi + (size_t)g * 4) = h;
    *(ushort4*)(elo + (size_t)g * 4) = l;
}

// ---------- kernel 3: MFMA bf16-split screener ----------
// Block: 64 rows, 256 threads (4 waves). Wave covers 32 j per jt-iter, jt 0..31.
// s_j = 2*dot' - ||e_j||^2; tracks per-row top-1 (value,index) + top-2 value.
// Rows with gap < 1e-4 are compacted for exact repair.
__global__ __launch_bounds__(256, 2) void k_screen(const float* __restrict__ z,
                                                   const unsigned short* __restrict__ ehi,
                                                   const unsigned short* __restrict__ elo,
                                                   const float* __restrict__ enf,
                                                   int* __restrict__ idx,
                                                   int* __restrict__ flaglist,
                                                   int* __restrict__ flagcnt) {
    __shared__ short Ah[64 * 256];     // 32 KB, XOR-swizzled
    __shared__ short Al[64 * 256];     // 32 KB
    __shared__ unsigned long long kbuf[4][64];
    __shared__ float sbuf[4][64];

    const int tid  = threadIdx.x;
    const int row0 = blockIdx.x * 64;

    // ---- stage z rows 64x256, split to bf16 hi/lo, swizzled LDS ----
    #pragma unroll
    for (int i = 0; i < 16; i++) {
        int q  = tid + 256 * i;        // float4 slot 0..4095
        int r  = q >> 6;               // row 0..63
        int c4 = q & 63;               // float4 within row
        float4 v = *(const float4*)(z + (size_t)(row0 + r) * E_DIM + c4 * 4);
        ushort4 h, l;
        h.x = bfr(v.x); l.x = bfr(v.x - bf2f(h.x));
        h.y = bfr(v.y); l.y = bfr(v.y - bf2f(h.y));
        h.z = bfr(v.z); l.z = bfr(v.z - bf2f(h.z));
        h.w = bfr(v.w); l.w = bfr(v.w - bf2f(h.w));
        int bo = (r * 512 + c4 * 8) ^ ((r & 7) << 4);
        *(ushort4*)((char*)Ah + bo) = h;
        *(ushort4*)((char*)Al + bo) = l;
    }
    __syncthreads();

    const int lane = tid & 63;
    const int w    = tid >> 6;         // wave 0..3
    const int l15  = lane & 15;
    const int lg   = lane >> 4;        // 0..3

    float best[16], sec[16];
    int   bj[16];
    #pragma unroll
    for (int s = 0; s < 16; s++) { best[s] = -3.0e38f; sec[s] = -3.0e38f; bj[s] = 4095; }

    for (int jt = 0; jt < 32; ++jt) {
        const int j0 = jt * 128 + w * 32 + l15;
        const int j1 = j0 + 16;
        f32x4 acc0[4], acc1[4];
        #pragma unroll
        for (int mi = 0; mi < 4; mi++) {
            acc0[mi] = (f32x4){0.f, 0.f, 0.f, 0.f};
            acc1[mi] = (f32x4){0.f, 0.f, 0.f, 0.f};
        }

        #pragma unroll
        for (int kt = 0; kt < 8; kt++) {
            const int k0 = kt * 32 + lg * 8;
            short8 ah[4], al[4];
            #pragma unroll
            for (int mi = 0; mi < 4; mi++) {
                int r  = mi * 16 + l15;
                int bo = (r * 512 + k0 * 2) ^ ((r & 7) << 4);
                ah[mi] = *(const short8*)((const char*)Ah + bo);
                al[mi] = *(const short8*)((const char*)Al + bo);
            }
            short8 bh0 = *(const short8*)(ehi + (size_t)j0 * E_DIM + k0);
            short8 bl0 = *(const short8*)(elo + (size_t)j0 * E_DIM + k0);
            short8 bh1 = *(const short8*)(ehi + (size_t)j1 * E_DIM + k0);
            short8 bl1 = *(const short8*)(elo + (size_t)j1 * E_DIM + k0);
            #pragma unroll
            for (int mi = 0; mi < 4; mi++) {
                acc0[mi] = __builtin_amdgcn_mfma_f32_16x16x32_bf16(ah[mi], bh0, acc0[mi], 0, 0, 0);
                acc0[mi] = __builtin_amdgcn_mfma_f32_16x16x32_bf16(al[mi], bh0, acc0[mi], 0, 0, 0);
                acc0[mi] = __builtin_amdgcn_mfma_f32_16x16x32_bf16(ah[mi], bl0, acc0[mi], 0, 0, 0);
                acc1[mi] = __builtin_amdgcn_mfma_f32_16x16x32_bf16(ah[mi], bh1, acc1[mi], 0, 0, 0);
                acc1[mi] = __builtin_amdgcn_mfma_f32_16x16x32_bf16(al[mi], bh1, acc1[mi], 0, 0, 0);
                acc1[mi] = __builtin_amdgcn_mfma_f32_16x16x32_bf16(ah[mi], bl1, acc1[mi], 0, 0, 0);
            }
        }

        const float en0 = enf[j0];
        const float en1 = enf[j1];
        #pragma unroll
        for (int mi = 0; mi < 4; mi++) {
            #pragma unroll
            for (int q = 0; q < 4; q++) {
                int   s  = mi * 4 + q;
                float s0 = 2.0f * acc0[mi][q] - en0;
                if (s0 > best[s]) { sec[s] = best[s]; best[s] = s0; bj[s] = j0; }
                else               sec[s] = fmaxf(sec[s], s0);
                float s1 = 2.0f * acc1[mi][q] - en1;
                if (s1 > best[s]) { sec[s] = best[s]; best[s] = s1; bj[s] = j1; }
                else               sec[s] = fmaxf(sec[s], s1);
            }
        }
    }

    // ---- 16-lane butterfly (merges j across l15; rows differ by lg) ----
    #pragma unroll
    for (int s = 0; s < 16; s++) {
        unsigned long long kk =
            ((unsigned long long)f2sort(best[s]) << 32) | (unsigned int)(4095 - bj[s]);
        float s2 = sec[s];
        #pragma unroll
        for (int off = 1; off < 16; off <<= 1) {
            unsigned long long ok = __shfl_xor(kk, off);
            float os = __shfl_xor(s2, off);
            float mv = keyval(kk), ov = keyval(ok);
            s2 = fmaxf(fmaxf(s2, os), fminf(mv, ov));
            if (ok > kk) kk = ok;
        }
        if (l15 == 0) {
            int r = (s >> 2) * 16 + lg * 4 + (s & 3);   // mi*16 + lg*4 + q
            kbuf[w][r] = kk;
            sbuf[w][r] = s2;
        }
    }
    __syncthreads();

    // ---- cross-wave merge + flag/compact ----
    if (tid < 64) {
        unsigned long long K = kbuf[0][tid];
        float S = sbuf[0][tid];
        #pragma unroll
        for (int wv = 1; wv < 4; wv++) {
            unsigned long long k2 = kbuf[wv][tid];
            float s2 = sbuf[wv][tid];
            S = fmaxf(fmaxf(S, s2), fminf(keyval(K), keyval(k2)));
            if (k2 > K) K = k2;
        }
        int grow = row0 + tid;
        idx[grow] = 4095 - (int)(K & 0xFFFFFFFFull);
        if (keyval(K) - S < 1e-4f) {
            int p = atomicAdd(flagcnt, 1);
            flaglist[p] = grow;
        }
    }
}

// ---------- kernel 4: exact collapsed-q repair for flagged rows ----------
// Replicates the PROVEN round-4 computation: ascending-k single-acc f32 fma
// dot; q = fl32( fl32(Cz+Ce) - 2*acc ); argmin with lowest-index ties.
__global__ __launch_bounds__(256) void k_repair(const float* __restrict__ z,
                                                const float* __restrict__ emb,
                                                const float* __restrict__ enf,
                                                const float* __restrict__ znf,
                                                const int* __restrict__ flagcnt,
                                                const int* __restrict__ flaglist,
                                                int* __restrict__ idx) {
    __shared__ float zs[8][E_DIM];
    const int tid = threadIdx.x;
    const int cnt = flagcnt[0];

    for (int base = blockIdx.x * 8; base < cnt; base += gridDim.x * 8) {
        __syncthreads();
        int nr = cnt - base; if (nr > 8) nr = 8;
        for (int i = tid; i < 8 * 64; i += 256) {      // 8 rows x 64 float4
            int r = i >> 6, c4 = i & 63;
            int grow = flaglist[base + (r < nr ? r : 0)];
            *(float4*)&zs[r][c4 * 4] = *(const float4*)(z + (size_t)grow * E_DIM + c4 * 4);
        }
        __syncthreads();

        const int r    = tid >> 5;                     // 0..7
        const int jl   = tid & 31;
        const int grow = flaglist[base + (r < nr ? r : 0)];
        const float Cz = znf[grow];

        unsigned long long bk = 0ull;
        for (int m = 0; m < 32; m++) {
            const int jA = jl + 128 * m, jB = jA + 32, jC = jA + 64, jD = jA + 96;
            float aA = 0.f, aB = 0.f, aC = 0.f, aD = 0.f;
            const float* eA = emb + (size_t)jA * E_DIM;
            const float* eB = emb + (size_t)jB * E_DIM;
            const float* eC = emb + (size_t)jC * E_DIM;
            const float* eD = emb + (size_t)jD * E_DIM;
            #pragma unroll 8
            for (int k4 = 0; k4 < 64; k4++) {
                float4 zq = *(const float4*)&zs[r][k4 * 4];
                float4 vA = *(const float4*)(eA + k4 * 4);
                float4 vB = *(const float4*)(eB + k4 * 4);
                float4 vC = *(const float4*)(eC + k4 * 4);
                float4 vD = *(const float4*)(eD + k4 * 4);
                aA = fmaf(zq.x, vA.x, aA); aA = fmaf(zq.y, vA.y, aA);
                aA = fmaf(zq.z, vA.z, aA); aA = fmaf(zq.w, vA.w, aA);
                aB = fmaf(zq.x, vB.x, aB); aB = fmaf(zq.y, vB.y, aB);
                aB = fmaf(zq.z, vB.z, aB); aB = fmaf(zq.w, vB.w, aB);
                aC = fmaf(zq.x, vC.x, aC); aC = fmaf(zq.y, vC.y, aC);
                aC = fmaf(zq.z, vC.z, aC); aC = fmaf(zq.w, vC.w, aC);
                aD = fmaf(zq.x, vD.x, aD); aD = fmaf(zq.y, vD.y, aD);
                aD = fmaf(zq.z, vD.z, aD); aD = fmaf(zq.w, vD.w, aD);
            }
            float qA = (Cz + enf[jA]) - 2.0f * aA;
            float qB = (Cz + enf[jB]) - 2.0f * aB;
            float qC = (Cz + enf[jC]) - 2.0f * aC;
            float qD = (Cz + enf[jD]) - 2.0f * aD;
            unsigned long long kA = ((unsigned long long)f2sort(-qA) << 32) | (unsigned int)(4095 - jA);
            unsigned long long kB = ((unsigned long long)f2sort(-qB) << 32) | (unsigned int)(4095 - jB);
            unsigned long long kC = ((unsigned long long)f2sort(-qC) << 32) | (unsigned int)(4095 - jC);
            unsigned long long kD = ((unsigned long long)f2sort(-qD) << 32) | (unsigned int)(4095 - jD);
            if (kA > bk) bk = kA;
            if (kB > bk) bk = kB;
            if (kC > bk) bk = kC;
            if (kD > bk) bk = kD;
        }
        #pragma unroll
        for (int off = 1; off < 32; off <<= 1) {
            unsigned long long ok = __shfl_xor(bk, off);
            if (ok > bk) bk = ok;
        }
        if (jl == 0 && r < nr)
            idx[grow] = 4095 - (int)(bk & 0xFFFFFFFFull);
    }
}

// ---------- kernel 5: epilogue ----------
// d_out FLOAT32: [loss(1) | one-hot(32768*4096) | z_q_st(32768*256) |
//                 emb(4096*256) | indices(32768)]
__global__ __launch_bounds__(256) void k_epilogue(const float* __restrict__ z,
                                                  const float* __restrict__ emb,
                                                  const int* __restrict__ idx,
                                                  float* __restrict__ out,
                                                  double* __restrict__ rowloss) {
    const int row  = blockIdx.x * 4 + (threadIdx.x >> 6);
    const int lane = threadIdx.x & 63;
    const int j    = idx[row];
    float4 zv = *(const float4*)(z   + (size_t)row * E_DIM + lane * 4);
    float4 ev = *(const float4*)(emb + (size_t)j   * E_DIM + lane * 4);

    float4 st;
    st.x = zv.x + (ev.x - zv.x);
    st.y = zv.y + (ev.y - zv.y);
    st.z = zv.z + (ev.z - zv.z);
    st.w = zv.w + (ev.w - zv.w);
    const size_t zq0 = 1ull + (size_t)N_ROWS * N_E;
    *(float4*)(out + zq0 + (size_t)row * E_DIM + lane * 4) = st;

    double dx = (double)ev.x - zv.x, dy = (double)ev.y - zv.y;
    double dz = (double)ev.z - zv.z, dw = (double)ev.w - zv.w;
    double s = dx * dx + dy * dy + dz * dz + dw * dw;
    #pragma unroll
    for (int off = 1; off < 64; off <<= 1) s += __shfl_xor(s, off);

    if (lane == 0) {
        rowloss[row] = s;
        out[1ull + (size_t)row * N_E + j] = 1.0f;
        const size_t ix0 = 1ull + (size_t)N_ROWS * N_E + (size_t)N_ROWS * E_DIM
                         + (size_t)N_E * E_DIM;
        out[ix0 + row] = (float)j;
    }
}

// ---------- kernel 6: deterministic loss reduce ----------
__global__ __launch_bounds__(256) void k_loss(const double* __restrict__ rowloss,
                                              float* __restrict__ out) {
    __shared__ double sm[256];
    double s = 0.0;
    for (int i = threadIdx.x; i < N_ROWS; i += 256) s += rowloss[i];
    sm[threadIdx.x] = s;
    __syncthreads();
    for (int h = 128; h > 0; h >>= 1) {
        if (threadIdx.x < h) sm[threadIdx.x] += sm[threadIdx.x + h];
        __syncthreads();
    }
    if (threadIdx.x == 0)
        out[0] = (float)(sm[0] / ((double)N_ROWS * (double)E_DIM));
}

extern "C" void kernel_launch(void* const* d_in, const int* in_sizes, int n_in,
                              void* d_out, int out_size, void* d_ws, size_t ws_size,
                              hipStream_t stream) {
    const float* z   = (const float*)d_in[0];
    const float* emb = (const float*)d_in[1];
    float* out = (float*)d_out;

    char* ws = (char*)d_ws;
    float*          enf      = (float*)(ws + 0);             // 16 KB
    float*          znf      = (float*)(ws + 16384);         // 128 KB
    int*            idx      = (int*)(ws + 147456);          // 128 KB
    int*            flagcnt  = (int*)(ws + 278528);          // 4 B (+pad)
    int*            flaglist = (int*)(ws + 278656);          // 128 KB
    double*         rowloss  = (double*)(ws + 409728);       // 256 KB
    unsigned short* ehi      = (unsigned short*)(ws + 671872);   // 2 MB
    unsigned short* elo      = (unsigned short*)(ws + 2769024);  // 2 MB

    // zero the one-hot region (f32 elements [1, 1+N*N_E)) and the flag counter
    hipMemsetAsync(out + 1, 0, (size_t)N_ROWS * (size_t)N_E * sizeof(float), stream);
    hipMemsetAsync(flagcnt, 0, sizeof(int), stream);

    // emb passthrough chunk: exact d2d copy
    const size_t emb0 = 1ull + (size_t)N_ROWS * N_E + (size_t)N_ROWS * E_DIM;
    hipMemcpyAsync(out + emb0, emb, (size_t)N_E * E_DIM * sizeof(float),
                   hipMemcpyDeviceToDevice, stream);

    k_rownorm <<<N_E / 4, 256, 0, stream>>>(emb, enf);
    k_rownorm <<<N_ROWS / 4, 256, 0, stream>>>(z, znf);
    k_embsplit<<<(N_E * E_DIM) / (4 * 256), 256, 0, stream>>>(emb, ehi, elo);
    k_screen  <<<N_ROWS / 64, 256, 0, stream>>>(z, ehi, elo, enf, idx, flaglist, flagcnt);
    k_repair  <<<256, 256, 0, stream>>>(z, emb, enf, znf, flagcnt, flaglist, idx);
    k_epilogue<<<N_ROWS / 4, 256, 0, stream>>>(z, emb, idx, out, rowloss);
    k_loss    <<<1, 256, 0, stream>>>(rowloss, out);
}

// Round 6
// 1823.136 us; speedup vs baseline: 1.3840x; 1.3840x over previous
//
#include <hip/hip_runtime.h>
#include <stdint.h>

#define N_ROWS 32768
#define N_E    4096
#define E_DIM  256

typedef __attribute__((ext_vector_type(8))) short short8;
typedef __attribute__((ext_vector_type(4))) float f32x4;

// sortable-uint encoding: order-preserving float -> uint
__device__ __forceinline__ unsigned int f2sort(float s) {
    unsigned int b = __float_as_uint(s);
    return (b & 0x80000000u) ? ~b : (b | 0x80000000u);
}
__device__ __forceinline__ float sort2f(unsigned int u) {
    unsigned int b = (u & 0x80000000u) ? (u ^ 0x80000000u) : ~u;
    return __uint_as_float(b);
}
__device__ __forceinline__ unsigned short bfr(float x) {   // f32 -> bf16 RNE
    unsigned int u = __float_as_uint(x);
    return (unsigned short)((u + 0x7fffu + ((u >> 16) & 1u)) >> 16);
}
__device__ __forceinline__ float bf2f(unsigned short h) {
    return __uint_as_float((unsigned int)h << 16);
}

// ---------- kernel 1: f32 row norms (f64 accumulate, cast f32) ----------
__global__ __launch_bounds__(256) void k_rownorm(const float* __restrict__ src,
                                                 float* __restrict__ outf) {
    int j = blockIdx.x * 4 + (threadIdx.x >> 6);
    int lane = threadIdx.x & 63;
    const float4* e4 = (const float4*)(src + (size_t)j * E_DIM);
    float4 v = e4[lane];
    double s = (double)v.x * v.x + (double)v.y * v.y + (double)v.z * v.z + (double)v.w * v.w;
    #pragma unroll
    for (int off = 1; off < 64; off <<= 1) s += __shfl_xor(s, off);
    if (lane == 0) outf[j] = (float)s;
}

// ---------- kernel 2: bf16 hi/lo split into MFMA fragment-major layout ----------
// frag-major short8 index: (row16blk)*512 + kt*64 + lg*16 + (row&15),
// holding k in [kt*32+lg*8, +8). Screen loads become 1KB-coalesced.
__global__ __launch_bounds__(256) void k_split(const float* __restrict__ src,
                                               unsigned short* __restrict__ hi,
                                               unsigned short* __restrict__ lo) {
    int c = blockIdx.x * 256 + threadIdx.x;   // 8-float chunk id
    int r   = c >> 5;
    int kc8 = c & 31;
    const float* p = src + (size_t)c * 8;
    float v[8];
    *(float4*)&v[0] = *(const float4*)p;
    *(float4*)&v[4] = *(const float4*)(p + 4);
    short8 h8, l8;
    #pragma unroll
    for (int t = 0; t < 8; t++) {
        unsigned short h = bfr(v[t]);
        h8[t] = (short)h;
        l8[t] = (short)bfr(v[t] - bf2f(h));
    }
    int kt = kc8 >> 2, lg = kc8 & 3;
    size_t o8 = (size_t)(r >> 4) * 512 + kt * 64 + lg * 16 + (r & 15);
    *(short8*)(hi + o8 * 8) = h8;
    *(short8*)(lo + o8 * 8) = l8;
}

// ---------- kernel 3: MFMA screener on the collapsed-f32 grid ----------
// Block: 64 rows, 4 waves; wave w owns j in [w*1024,(w+1)*1024), 16 passes of 64 j.
// q = fl32(fl32(Cz+Ce) - 2*acc) tracked as min-key (q, j). Fragility: residue
// within 1.5e-7 of the rounding boundary -> candidate for exact repair.
__global__ __launch_bounds__(256, 2) void k_screen(
        const unsigned short* __restrict__ zhi, const unsigned short* __restrict__ zlo,
        const unsigned short* __restrict__ ehi, const unsigned short* __restrict__ elo,
        const float* __restrict__ enf, const float* __restrict__ znf,
        int* __restrict__ idx, int* __restrict__ flaglist, int* __restrict__ flagcnt) {
    __shared__ unsigned long long kbuf[4][64];
    __shared__ float qbuf[4][64];

    const int tid  = threadIdx.x;
    const int lane = tid & 63;
    const int w    = tid >> 6;
    const int l15  = lane & 15;
    const int lg   = lane >> 4;
    const int rb0  = blockIdx.x * 4;           // base 16-row block

    const short8* Ah = (const short8*)zhi;
    const short8* Al = (const short8*)zlo;
    const short8* Bh = (const short8*)ehi;
    const short8* Bl = (const short8*)elo;

    float czs[16];
    #pragma unroll
    for (int mi = 0; mi < 4; mi++)
        #pragma unroll
        for (int q = 0; q < 4; q++)
            czs[mi * 4 + q] = znf[(rb0 + mi) * 16 + lg * 4 + q];

    unsigned long long K1[16];
    float Qf[16];
    #pragma unroll
    for (int s = 0; s < 16; s++) { K1[s] = ~0ull; Qf[s] = __uint_as_float(0x7F800000u); }

    for (int p = 0; p < 16; ++p) {
        const int jb0 = w * 64 + p * 4;        // 16-j block index
        f32x4 acc[2][4][2];
        #pragma unroll
        for (int i = 0; i < 2; i++)
            #pragma unroll
            for (int mi = 0; mi < 4; mi++)
                #pragma unroll
                for (int jp = 0; jp < 2; jp++)
                    acc[i][mi][jp] = (f32x4){0.f, 0.f, 0.f, 0.f};

        #pragma unroll
        for (int kt = 0; kt < 8; kt++) {
            short8 ah[4], al[4];
            #pragma unroll
            for (int mi = 0; mi < 4; mi++) {
                int ai = (rb0 + mi) * 512 + kt * 64 + lane;
                ah[mi] = Ah[ai];
                al[mi] = Al[ai];
            }
            #pragma unroll
            for (int i = 0; i < 2; i++) {
                int bi = (jb0 + i * 2) * 512 + kt * 64 + lane;
                short8 bh0 = Bh[bi],       bl0 = Bl[bi];
                short8 bh1 = Bh[bi + 512], bl1 = Bl[bi + 512];
                #pragma unroll
                for (int mi = 0; mi < 4; mi++) {
                    acc[i][mi][0] = __builtin_amdgcn_mfma_f32_16x16x32_bf16(ah[mi], bh0, acc[i][mi][0], 0, 0, 0);
                    acc[i][mi][1] = __builtin_amdgcn_mfma_f32_16x16x32_bf16(ah[mi], bh1, acc[i][mi][1], 0, 0, 0);
                    acc[i][mi][0] = __builtin_amdgcn_mfma_f32_16x16x32_bf16(al[mi], bh0, acc[i][mi][0], 0, 0, 0);
                    acc[i][mi][1] = __builtin_amdgcn_mfma_f32_16x16x32_bf16(al[mi], bh1, acc[i][mi][1], 0, 0, 0);
                    acc[i][mi][0] = __builtin_amdgcn_mfma_f32_16x16x32_bf16(ah[mi], bl0, acc[i][mi][0], 0, 0, 0);
                    acc[i][mi][1] = __builtin_amdgcn_mfma_f32_16x16x32_bf16(ah[mi], bl1, acc[i][mi][1], 0, 0, 0);
                }
            }
        }

        #pragma unroll
        for (int i = 0; i < 2; i++) {
            #pragma unroll
            for (int jp = 0; jp < 2; jp++) {
                int j = (jb0 + i * 2 + jp) * 16 + l15;
                float Ce = enf[j];
                #pragma unroll
                for (int mi = 0; mi < 4; mi++) {
                    #pragma unroll
                    for (int q = 0; q < 4; q++) {
                        int s = mi * 4 + q;
                        float av = acc[i][mi][jp][q];
                        float A  = czs[s] + Ce;                 // fl32(Cz+Ce)
                        float qv = fmaf(-2.0f, av, A);          // fl32(A-2acc)
                        unsigned long long kk =
                            ((unsigned long long)f2sort(qv) << 32) | (unsigned int)j;
                        if (kk < K1[s]) K1[s] = kk;
                        float res = (A - qv) - 2.0f * av;       // exact rounding residue
                        float u = __uint_as_float(__float_as_uint(qv) & 0x7F800000u)
                                  * 1.1920929e-7f;              // ulp(qv)
                        if (fabsf(res) > fmaf(0.5f, u, -1.5e-7f))
                            Qf[s] = fminf(Qf[s], qv);
                    }
                }
            }
        }
    }

    // merge over the 16 l15-lanes (same lg -> same rows)
    #pragma unroll
    for (int s = 0; s < 16; s++) {
        unsigned long long K = K1[s];
        float Q = Qf[s];
        #pragma unroll
        for (int off = 1; off < 16; off <<= 1) {
            unsigned long long ok = __shfl_xor(K, off);
            float oq = __shfl_xor(Q, off);
            if (ok < K) K = ok;
            Q = fminf(Q, oq);
        }
        if (l15 == 0) {
            int r = (s >> 2) * 16 + lg * 4 + (s & 3);
            kbuf[w][r] = K;
            qbuf[w][r] = Q;
        }
    }
    __syncthreads();

    if (tid < 64) {
        unsigned long long K = kbuf[0][tid];
        float Q = qbuf[0][tid];
        #pragma unroll
        for (int wv = 1; wv < 4; wv++) {
            unsigned long long k2 = kbuf[wv][tid];
            float q2 = qbuf[wv][tid];
            if (k2 < K) K = k2;
            Q = fminf(Q, q2);
        }
        int grow = rb0 * 16 + tid;
        idx[grow] = (int)(K & 0xFFFFFFFFull);
        float qwin = sort2f((unsigned int)(K >> 32));
        float u = __uint_as_float(__float_as_uint(qwin) & 0x7F800000u) * 1.1920929e-7f;
        if (Q <= fmaf(2.0f, u, qwin)) {       // fragile candidate within 2 grid steps
            int pp = atomicAdd(flagcnt, 1);
            flaglist[pp] = grow;
        }
    }
}

// ---------- kernel 4: exact np-replica repair, paired rows ----------
// ascending-k single-acc f32 fma chain; q = fl32(fl32(Cz+Ce) - 2*acc);
// argmin with lowest-index ties. Two rows share each emb stream.
__global__ __launch_bounds__(256) void k_repair(const float* __restrict__ z,
                                                const float* __restrict__ emb,
                                                const float* __restrict__ enf,
                                                const float* __restrict__ znf,
                                                const int* __restrict__ flagcnt,
                                                const int* __restrict__ flaglist,
                                                int* __restrict__ idx) {
    __shared__ float zs[16][E_DIM];
    const int tid = threadIdx.x;
    const int cnt = flagcnt[0];

    for (int base = blockIdx.x * 16; base < cnt; base += gridDim.x * 16) {
        __syncthreads();
        for (int i = tid; i < 16 * 64; i += 256) {
            int r = i >> 6, c4 = i & 63;
            int fi = base + r;
            int grow = flaglist[fi < cnt ? fi : base];
            *(float4*)&zs[r][c4 * 4] = *(const float4*)(z + (size_t)grow * E_DIM + c4 * 4);
        }
        __syncthreads();

        const int g  = tid >> 5;
        const int jl = tid & 31;
        const int fA = base + g * 2, fB = fA + 1;
        const int gA = flaglist[fA < cnt ? fA : base];
        const int gB = flaglist[fB < cnt ? fB : base];
        const float CzA = znf[gA], CzB = znf[gB];
        const int rA = g * 2, rB = rA + 1;

        unsigned long long bkA = ~0ull, bkB = ~0ull;
        for (int m = 0; m < 32; m++) {
            const int j0 = jl + 128 * m;
            const float* e0 = emb + (size_t)(j0     ) * E_DIM;
            const float* e1 = emb + (size_t)(j0 + 32) * E_DIM;
            const float* e2 = emb + (size_t)(j0 + 64) * E_DIM;
            const float* e3 = emb + (size_t)(j0 + 96) * E_DIM;
            float aA0 = 0.f, aA1 = 0.f, aA2 = 0.f, aA3 = 0.f;
            float aB0 = 0.f, aB1 = 0.f, aB2 = 0.f, aB3 = 0.f;
            #pragma unroll 4
            for (int k4 = 0; k4 < 64; k4++) {
                float4 zA = *(const float4*)&zs[rA][k4 * 4];
                float4 zB = *(const float4*)&zs[rB][k4 * 4];
                float4 v0 = *(const float4*)(e0 + k4 * 4);
                float4 v1 = *(const float4*)(e1 + k4 * 4);
                float4 v2 = *(const float4*)(e2 + k4 * 4);
                float4 v3 = *(const float4*)(e3 + k4 * 4);
                aA0 = fmaf(zA.x, v0.x, aA0); aA0 = fmaf(zA.y, v0.y, aA0);
                aA0 = fmaf(zA.z, v0.z, aA0); aA0 = fmaf(zA.w, v0.w, aA0);
                aA1 = fmaf(zA.x, v1.x, aA1); aA1 = fmaf(zA.y, v1.y, aA1);
                aA1 = fmaf(zA.z, v1.z, aA1); aA1 = fmaf(zA.w, v1.w, aA1);
                aA2 = fmaf(zA.x, v2.x, aA2); aA2 = fmaf(zA.y, v2.y, aA2);
                aA2 = fmaf(zA.z, v2.z, aA2); aA2 = fmaf(zA.w, v2.w, aA2);
                aA3 = fmaf(zA.x, v3.x, aA3); aA3 = fmaf(zA.y, v3.y, aA3);
                aA3 = fmaf(zA.z, v3.z, aA3); aA3 = fmaf(zA.w, v3.w, aA3);
                aB0 = fmaf(zB.x, v0.x, aB0); aB0 = fmaf(zB.y, v0.y, aB0);
                aB0 = fmaf(zB.z, v0.z, aB0); aB0 = fmaf(zB.w, v0.w, aB0);
                aB1 = fmaf(zB.x, v1.x, aB1); aB1 = fmaf(zB.y, v1.y, aB1);
                aB1 = fmaf(zB.z, v1.z, aB1); aB1 = fmaf(zB.w, v1.w, aB1);
                aB2 = fmaf(zB.x, v2.x, aB2); aB2 = fmaf(zB.y, v2.y, aB2);
                aB2 = fmaf(zB.z, v2.z, aB2); aB2 = fmaf(zB.w, v2.w, aB2);
                aB3 = fmaf(zB.x, v3.x, aB3); aB3 = fmaf(zB.y, v3.y, aB3);
                aB3 = fmaf(zB.z, v3.z, aB3); aB3 = fmaf(zB.w, v3.w, aB3);
            }
            float en0 = enf[j0], en1 = enf[j0 + 32], en2 = enf[j0 + 64], en3 = enf[j0 + 96];
            float qA0 = (CzA + en0) - 2.0f * aA0, qA1 = (CzA + en1) - 2.0f * aA1;
            float qA2 = (CzA + en2) - 2.0f * aA2, qA3 = (CzA + en3) - 2.0f * aA3;
            float qB0 = (CzB + en0) - 2.0f * aB0, qB1 = (CzB + en1) - 2.0f * aB1;
            float qB2 = (CzB + en2) - 2.0f * aB2, qB3 = (CzB + en3) - 2.0f * aB3;
            unsigned long long k;
            k = ((unsigned long long)f2sort(qA0) << 32) | (unsigned int)(j0     ); if (k < bkA) bkA = k;
            k = ((unsigned long long)f2sort(qA1) << 32) | (unsigned int)(j0 + 32); if (k < bkA) bkA = k;
            k = ((unsigned long long)f2sort(qA2) << 32) | (unsigned int)(j0 + 64); if (k < bkA) bkA = k;
            k = ((unsigned long long)f2sort(qA3) << 32) | (unsigned int)(j0 + 96); if (k < bkA) bkA = k;
            k = ((unsigned long long)f2sort(qB0) << 32) | (unsigned int)(j0     ); if (k < bkB) bkB = k;
            k = ((unsigned long long)f2sort(qB1) << 32) | (unsigned int)(j0 + 32); if (k < bkB) bkB = k;
            k = ((unsigned long long)f2sort(qB2) << 32) | (unsigned int)(j0 + 64); if (k < bkB) bkB = k;
            k = ((unsigned long long)f2sort(qB3) << 32) | (unsigned int)(j0 + 96); if (k < bkB) bkB = k;
        }
        #pragma unroll
        for (int off = 1; off < 32; off <<= 1) {
            unsigned long long oA = __shfl_xor(bkA, off);
            unsigned long long oB = __shfl_xor(bkB, off);
            if (oA < bkA) bkA = oA;
            if (oB < bkB) bkB = oB;
        }
        if (jl == 0) {
            if (fA < cnt) idx[gA] = (int)(bkA & 0xFFFFFFFFull);
            if (fB < cnt) idx[gB] = (int)(bkB & 0xFFFFFFFFull);
        }
    }
}

// ---------- kernel 5: epilogue ----------
// d_out FLOAT32: [loss(1) | one-hot(32768*4096) | z_q_st(32768*256) |
//                 emb(4096*256) | indices(32768)]
__global__ __launch_bounds__(256) void k_epilogue(const float* __restrict__ z,
                                                  const float* __restrict__ emb,
                                                  const int* __restrict__ idx,
                                                  float* __restrict__ out,
                                                  double* __restrict__ rowloss) {
    const int row  = blockIdx.x * 4 + (threadIdx.x >> 6);
    const int lane = threadIdx.x & 63;
    const int j    = idx[row];
    float4 zv = *(const float4*)(z   + (size_t)row * E_DIM + lane * 4);
    float4 ev = *(const float4*)(emb + (size_t)j   * E_DIM + lane * 4);

    float4 st;
    st.x = zv.x + (ev.x - zv.x);
    st.y = zv.y + (ev.y - zv.y);
    st.z = zv.z + (ev.z - zv.z);
    st.w = zv.w + (ev.w - zv.w);
    const size_t zq0 = 1ull + (size_t)N_ROWS * N_E;
    *(float4*)(out + zq0 + (size_t)row * E_DIM + lane * 4) = st;

    double dx = (double)ev.x - zv.x, dy = (double)ev.y - zv.y;
    double dz = (double)ev.z - zv.z, dw = (double)ev.w - zv.w;
    double s = dx * dx + dy * dy + dz * dz + dw * dw;
    #pragma unroll
    for (int off = 1; off < 64; off <<= 1) s += __shfl_xor(s, off);

    if (lane == 0) {
        rowloss[row] = s;
        out[1ull + (size_t)row * N_E + j] = 1.0f;
        const size_t ix0 = 1ull + (size_t)N_ROWS * N_E + (size_t)N_ROWS * E_DIM
                         + (size_t)N_E * E_DIM;
        out[ix0 + row] = (float)j;
    }
}

// ---------- kernel 6: deterministic loss reduce ----------
__global__ __launch_bounds__(256) void k_loss(const double* __restrict__ rowloss,
                                              float* __restrict__ out) {
    __shared__ double sm[256];
    double s = 0.0;
    for (int i = threadIdx.x; i < N_ROWS; i += 256) s += rowloss[i];
    sm[threadIdx.x] = s;
    __syncthreads();
    for (int h = 128; h > 0; h >>= 1) {
        if (threadIdx.x < h) sm[threadIdx.x] += sm[threadIdx.x + h];
        __syncthreads();
    }
    if (threadIdx.x == 0)
        out[0] = (float)(sm[0] / ((double)N_ROWS * (double)E_DIM));
}

extern "C" void kernel_launch(void* const* d_in, const int* in_sizes, int n_in,
                              void* d_out, int out_size, void* d_ws, size_t ws_size,
                              hipStream_t stream) {
    const float* z   = (const float*)d_in[0];
    const float* emb = (const float*)d_in[1];
    float* out = (float*)d_out;

    char* ws = (char*)d_ws;
    float*          enf      = (float*)(ws + 0);                 // 16 KB
    float*          znf      = (float*)(ws + 16384);             // 128 KB
    int*            idx      = (int*)(ws + 147456);              // 128 KB
    int*            flagcnt  = (int*)(ws + 278528);              // 128 B
    int*            flaglist = (int*)(ws + 278656);              // 128 KB
    double*         rowloss  = (double*)(ws + 409728);           // 256 KB
    unsigned short* zhi      = (unsigned short*)(ws + 671872);   // 16 MB
    unsigned short* zlo      = (unsigned short*)(ws + 17449088); // 16 MB
    unsigned short* ehi      = (unsigned short*)(ws + 34226304); // 2 MB
    unsigned short* elo      = (unsigned short*)(ws + 36323456); // 2 MB

    // zero one-hot region + flag counter
    hipMemsetAsync(out + 1, 0, (size_t)N_ROWS * (size_t)N_E * sizeof(float), stream);
    hipMemsetAsync(flagcnt, 0, sizeof(int), stream);

    // emb passthrough chunk: exact d2d copy
    const size_t emb0 = 1ull + (size_t)N_ROWS * N_E + (size_t)N_ROWS * E_DIM;
    hipMemcpyAsync(out + emb0, emb, (size_t)N_E * E_DIM * sizeof(float),
                   hipMemcpyDeviceToDevice, stream);

    k_rownorm <<<N_E / 4, 256, 0, stream>>>(emb, enf);
    k_rownorm <<<N_ROWS / 4, 256, 0, stream>>>(z, znf);
    k_split   <<<N_ROWS / 8, 256, 0, stream>>>(z, zhi, zlo);
    k_split   <<<N_E / 8, 256, 0, stream>>>(emb, ehi, elo);
    k_screen  <<<N_ROWS / 64, 256, 0, stream>>>(zhi, zlo, ehi, elo, enf, znf,
                                                idx, flaglist, flagcnt);
    k_repair  <<<256, 256, 0, stream>>>(z, emb, enf, znf, flagcnt, flaglist, idx);
    k_epilogue<<<N_ROWS / 4, 256, 0, stream>>>(z, emb, idx, out, rowloss);
    k_loss    <<<1, 256, 0, stream>>>(rowloss, out);
}

// Round 7
// 922.161 us; speedup vs baseline: 2.7362x; 1.9770x over previous
//
#include <hip/hip_runtime.h>
#include <stdint.h>

#define N_ROWS 32768
#define N_E    4096
#define E_DIM  256

typedef __attribute__((ext_vector_type(8))) short short8;
typedef __attribute__((ext_vector_type(4))) float f32x4;

// sortable-uint encoding: order-preserving float -> uint
__device__ __forceinline__ unsigned int f2sort(float s) {
    unsigned int b = __float_as_uint(s);
    return (b & 0x80000000u) ? ~b : (b | 0x80000000u);
}
__device__ __forceinline__ float sort2f(unsigned int u) {
    unsigned int b = (u & 0x80000000u) ? (u ^ 0x80000000u) : ~u;
    return __uint_as_float(b);
}
__device__ __forceinline__ unsigned short bfr(float x) {   // f32 -> bf16 RNE
    unsigned int u = __float_as_uint(x);
    return (unsigned short)((u + 0x7fffu + ((u >> 16) & 1u)) >> 16);
}
__device__ __forceinline__ float bf2f(unsigned short h) {
    return __uint_as_float((unsigned int)h << 16);
}

// ---------- kernel 1: f32 row norms (f64 accumulate, cast f32) ----------
__global__ __launch_bounds__(256) void k_rownorm(const float* __restrict__ src,
                                                 float* __restrict__ outf) {
    int j = blockIdx.x * 4 + (threadIdx.x >> 6);
    int lane = threadIdx.x & 63;
    const float4* e4 = (const float4*)(src + (size_t)j * E_DIM);
    float4 v = e4[lane];
    double s = (double)v.x * v.x + (double)v.y * v.y + (double)v.z * v.z + (double)v.w * v.w;
    #pragma unroll
    for (int off = 1; off < 64; off <<= 1) s += __shfl_xor(s, off);
    if (lane == 0) outf[j] = (float)s;
}

// ---------- kernel 2: bf16 hi/lo split into MFMA fragment-major layout ----------
__global__ __launch_bounds__(256) void k_split(const float* __restrict__ src,
                                               unsigned short* __restrict__ hi,
                                               unsigned short* __restrict__ lo) {
    int c = blockIdx.x * 256 + threadIdx.x;   // 8-float chunk id
    int r   = c >> 5;
    int kc8 = c & 31;
    const float* p = src + (size_t)c * 8;
    float v[8];
    *(float4*)&v[0] = *(const float4*)p;
    *(float4*)&v[4] = *(const float4*)(p + 4);
    short8 h8, l8;
    #pragma unroll
    for (int t = 0; t < 8; t++) {
        unsigned short h = bfr(v[t]);
        h8[t] = (short)h;
        l8[t] = (short)bfr(v[t] - bf2f(h));
    }
    int kt = kc8 >> 2, lg = kc8 & 3;
    size_t o8 = (size_t)(r >> 4) * 512 + kt * 64 + lg * 16 + (r & 15);
    *(short8*)(hi + o8 * 8) = h8;
    *(short8*)(lo + o8 * 8) = l8;
}

// ---------- kernel 3: MFMA screener on the collapsed-f32 grid ----------
// 64 rows/block, 4 waves; wave w owns j-window [w*1024,(w+1)*1024) in 32 p-tiles
// of 32 j. A-frags staged ONCE into LDS; B double-buffered in registers.
__global__ __launch_bounds__(256, 2) void k_screen(
        const unsigned short* __restrict__ zhi, const unsigned short* __restrict__ zlo,
        const unsigned short* __restrict__ ehi, const unsigned short* __restrict__ elo,
        const float* __restrict__ enf, const float* __restrict__ znf,
        int* __restrict__ idx, int* __restrict__ flaglist, int* __restrict__ flagcnt) {
    __shared__ short8 ldsA[4096];              // 64 KB: [0,2048)=Ah, [2048,4096)=Al
    short8* AhL = ldsA;
    short8* AlL = ldsA + 2048;

    const int tid  = threadIdx.x;
    const int lane = tid & 63;
    const int w    = tid >> 6;
    const int l15  = lane & 15;
    const int lg   = lane >> 4;
    const int rb0  = blockIdx.x * 4;           // base 16-row frag block

    const short8* Ahg = (const short8*)zhi;
    const short8* Alg = (const short8*)zlo;
    const short8* Bh  = (const short8*)ehi;
    const short8* Bl  = (const short8*)elo;

    // ---- stage A hi/lo frag-major slices (once) ----
    #pragma unroll
    for (int i = 0; i < 8; i++) {
        int ii = tid + 256 * i;                // 0..2047
        int mi = ii >> 9, q = ii & 511;
        AhL[ii] = Ahg[(size_t)(rb0 + mi) * 512 + q];
        AlL[ii] = Alg[(size_t)(rb0 + mi) * 512 + q];
    }
    __syncthreads();

    float czs[16];
    #pragma unroll
    for (int mi = 0; mi < 4; mi++)
        #pragma unroll
        for (int q = 0; q < 4; q++)
            czs[mi * 4 + q] = znf[(rb0 + mi) * 16 + lg * 4 + q];

    unsigned long long K1[16];
    float Qf[16];
    #pragma unroll
    for (int s = 0; s < 16; s++) { K1[s] = ~0ull; Qf[s] = __uint_as_float(0x7F800000u); }

    for (int p = 0; p < 32; ++p) {
        const int jb = w * 64 + p * 2;         // 16-j block index
        const int bbase = jb * 512 + lane;
        f32x4 acc[4][2];
        #pragma unroll
        for (int mi = 0; mi < 4; mi++) {
            acc[mi][0] = (f32x4){0.f, 0.f, 0.f, 0.f};
            acc[mi][1] = (f32x4){0.f, 0.f, 0.f, 0.f};
        }

        short8 pb[2][4];
        pb[0][0] = Bh[bbase];       pb[0][1] = Bh[bbase + 512];
        pb[0][2] = Bl[bbase];       pb[0][3] = Bl[bbase + 512];

        #pragma unroll
        for (int kt = 0; kt < 8; kt++) {
            const int cur = kt & 1, nxt = cur ^ 1;
            if (kt < 7) {
                int o = bbase + (kt + 1) * 64;
                pb[nxt][0] = Bh[o];       pb[nxt][1] = Bh[o + 512];
                pb[nxt][2] = Bl[o];       pb[nxt][3] = Bl[o + 512];
            }
            short8 ah[4], al[4];
            #pragma unroll
            for (int mi = 0; mi < 4; mi++) {
                int ai = mi * 512 + kt * 64 + lane;
                ah[mi] = AhL[ai];
                al[mi] = AlL[ai];
            }
            #pragma unroll
            for (int mi = 0; mi < 4; mi++) {
                acc[mi][0] = __builtin_amdgcn_mfma_f32_16x16x32_bf16(ah[mi], pb[cur][0], acc[mi][0], 0, 0, 0);
                acc[mi][1] = __builtin_amdgcn_mfma_f32_16x16x32_bf16(ah[mi], pb[cur][1], acc[mi][1], 0, 0, 0);
                acc[mi][0] = __builtin_amdgcn_mfma_f32_16x16x32_bf16(al[mi], pb[cur][0], acc[mi][0], 0, 0, 0);
                acc[mi][1] = __builtin_amdgcn_mfma_f32_16x16x32_bf16(al[mi], pb[cur][1], acc[mi][1], 0, 0, 0);
                acc[mi][0] = __builtin_amdgcn_mfma_f32_16x16x32_bf16(ah[mi], pb[cur][2], acc[mi][0], 0, 0, 0);
                acc[mi][1] = __builtin_amdgcn_mfma_f32_16x16x32_bf16(ah[mi], pb[cur][3], acc[mi][1], 0, 0, 0);
            }
        }

        #pragma unroll
        for (int jp = 0; jp < 2; jp++) {
            int j = (jb + jp) * 16 + l15;
            float Ce = enf[j];
            #pragma unroll
            for (int mi = 0; mi < 4; mi++) {
                #pragma unroll
                for (int q = 0; q < 4; q++) {
                    int s = mi * 4 + q;
                    float av = acc[mi][jp][q];
                    float A  = czs[s] + Ce;                 // fl32(Cz+Ce)
                    float qv = fmaf(-2.0f, av, A);          // fl32(A-2acc)
                    unsigned long long kk =
                        ((unsigned long long)f2sort(qv) << 32) | (unsigned int)j;
                    if (kk < K1[s]) K1[s] = kk;
                    float res = (A - qv) - 2.0f * av;       // exact rounding residue
                    float u = __uint_as_float(__float_as_uint(qv) & 0x7F800000u)
                              * 1.1920929e-7f;              // ulp(qv)
                    if (fabsf(res) > fmaf(0.5f, u, -1.5e-7f))
                        Qf[s] = fminf(Qf[s], qv);
                }
            }
        }
    }

    // A-LDS no longer needed: overlay reduction buffers (sync first)
    __syncthreads();
    unsigned long long* kbuf = (unsigned long long*)ldsA;          // [4][64]
    float* qbuf = (float*)((char*)ldsA + 2048);                    // [4][64]

    #pragma unroll
    for (int s = 0; s < 16; s++) {
        unsigned long long K = K1[s];
        float Q = Qf[s];
        #pragma unroll
        for (int off = 1; off < 16; off <<= 1) {
            unsigned long long ok = __shfl_xor(K, off);
            float oq = __shfl_xor(Q, off);
            if (ok < K) K = ok;
            Q = fminf(Q, oq);
        }
        if (l15 == 0) {
            int r = (s >> 2) * 16 + lg * 4 + (s & 3);
            kbuf[w * 64 + r] = K;
            qbuf[w * 64 + r] = Q;
        }
    }
    __syncthreads();

    if (tid < 64) {
        unsigned long long K = kbuf[tid];
        float Q = qbuf[tid];
        #pragma unroll
        for (int wv = 1; wv < 4; wv++) {
            unsigned long long k2 = kbuf[wv * 64 + tid];
            float q2 = qbuf[wv * 64 + tid];
            if (k2 < K) K = k2;
            Q = fminf(Q, q2);
        }
        int grow = rb0 * 16 + tid;
        idx[grow] = (int)(K & 0xFFFFFFFFull);
        float qwin = sort2f((unsigned int)(K >> 32));
        float u = __uint_as_float(__float_as_uint(qwin) & 0x7F800000u) * 1.1920929e-7f;
        if (Q <= fmaf(2.0f, u, qwin)) {       // fragile candidate within 2 grid steps
            int pp = atomicAdd(flagcnt, 1);
            flaglist[pp] = grow;
        }
    }
}

// ---------- kernel 4: exact np-replica repair ----------
// 4 flagged rows per block; thread = 4 j-streams x 4 rows (16 chains) sharing
// each emb load. ascending-k single-acc f32 fma chain; q = fl32(fl32(Cz+Ce)-2acc).
__global__ __launch_bounds__(256) void k_repair(const float* __restrict__ z,
                                                const float* __restrict__ emb,
                                                const float* __restrict__ enf,
                                                const float* __restrict__ znf,
                                                const int* __restrict__ flagcnt,
                                                const int* __restrict__ flaglist,
                                                int* __restrict__ idx) {
    __shared__ float zr[4][E_DIM];
    __shared__ unsigned long long redk[4][4];   // [wave][row]
    const int tid = threadIdx.x;
    const int cnt = flagcnt[0];

    for (int base = blockIdx.x * 4; base < cnt; base += gridDim.x * 4) {
        __syncthreads();                         // protect zr/redk reuse
        int gr[4];
        #pragma unroll
        for (int r = 0; r < 4; r++) {
            int fi = base + r;
            gr[r] = flaglist[fi < cnt ? fi : base];
        }
        #pragma unroll
        for (int r = 0; r < 4; r++)
            zr[r][tid] = z[(size_t)gr[r] * E_DIM + tid];
        __syncthreads();

        float Cz[4];
        #pragma unroll
        for (int r = 0; r < 4; r++) Cz[r] = znf[gr[r]];

        unsigned long long bk[4];
        #pragma unroll
        for (int r = 0; r < 4; r++) bk[r] = ~0ull;

        #pragma unroll
        for (int g = 0; g < 4; g++) {
            const int j0 = tid + 1024 * g;       // streams j0, +256, +512, +768
            const float* e0 = emb + (size_t)(j0      ) * E_DIM;
            const float* e1 = emb + (size_t)(j0 + 256) * E_DIM;
            const float* e2 = emb + (size_t)(j0 + 512) * E_DIM;
            const float* e3 = emb + (size_t)(j0 + 768) * E_DIM;
            float a[4][4];                       // [row][stream]
            #pragma unroll
            for (int r = 0; r < 4; r++)
                #pragma unroll
                for (int s = 0; s < 4; s++) a[r][s] = 0.0f;

            #pragma unroll 4
            for (int k4 = 0; k4 < 64; k4++) {
                float4 v0 = *(const float4*)(e0 + k4 * 4);
                float4 v1 = *(const float4*)(e1 + k4 * 4);
                float4 v2 = *(const float4*)(e2 + k4 * 4);
                float4 v3 = *(const float4*)(e3 + k4 * 4);
                #pragma unroll
                for (int r = 0; r < 4; r++) {
                    float4 zq = *(const float4*)&zr[r][k4 * 4];
                    a[r][0] = fmaf(zq.x, v0.x, a[r][0]); a[r][0] = fmaf(zq.y, v0.y, a[r][0]);
                    a[r][0] = fmaf(zq.z, v0.z, a[r][0]); a[r][0] = fmaf(zq.w, v0.w, a[r][0]);
                    a[r][1] = fmaf(zq.x, v1.x, a[r][1]); a[r][1] = fmaf(zq.y, v1.y, a[r][1]);
                    a[r][1] = fmaf(zq.z, v1.z, a[r][1]); a[r][1] = fmaf(zq.w, v1.w, a[r][1]);
                    a[r][2] = fmaf(zq.x, v2.x, a[r][2]); a[r][2] = fmaf(zq.y, v2.y, a[r][2]);
                    a[r][2] = fmaf(zq.z, v2.z, a[r][2]); a[r][2] = fmaf(zq.w, v2.w, a[r][2]);
                    a[r][3] = fmaf(zq.x, v3.x, a[r][3]); a[r][3] = fmaf(zq.y, v3.y, a[r][3]);
                    a[r][3] = fmaf(zq.z, v3.z, a[r][3]); a[r][3] = fmaf(zq.w, v3.w, a[r][3]);
                }
            }
            float en[4] = {enf[j0], enf[j0 + 256], enf[j0 + 512], enf[j0 + 768]};
            #pragma unroll
            for (int r = 0; r < 4; r++) {
                #pragma unroll
                for (int s = 0; s < 4; s++) {
                    float q = (Cz[r] + en[s]) - 2.0f * a[r][s];
                    unsigned long long k =
                        ((unsigned long long)f2sort(q) << 32) | (unsigned int)(j0 + 256 * s);
                    if (k < bk[r]) bk[r] = k;
                }
            }
        }

        const int w = tid >> 6;
        #pragma unroll
        for (int r = 0; r < 4; r++) {
            unsigned long long K = bk[r];
            #pragma unroll
            for (int off = 1; off < 64; off <<= 1) {
                unsigned long long ok = __shfl_xor(K, off);
                if (ok < K) K = ok;
            }
            if ((tid & 63) == 0) redk[w][r] = K;
        }
        __syncthreads();
        if (tid < 4 && base + tid < cnt) {
            unsigned long long K = redk[0][tid];
            #pragma unroll
            for (int wv = 1; wv < 4; wv++)
                if (redk[wv][tid] < K) K = redk[wv][tid];
            idx[gr[tid]] = (int)(K & 0xFFFFFFFFull);
        }
    }
}

// ---------- kernel 5: epilogue ----------
// d_out FLOAT32: [loss(1) | one-hot(32768*4096) | z_q_st(32768*256) |
//                 emb(4096*256) | indices(32768)]
__global__ __launch_bounds__(256) void k_epilogue(const float* __restrict__ z,
                                                  const float* __restrict__ emb,
                                                  const int* __restrict__ idx,
                                                  float* __restrict__ out,
                                                  double* __restrict__ rowloss) {
    const int row  = blockIdx.x * 4 + (threadIdx.x >> 6);
    const int lane = threadIdx.x & 63;
    const int j    = idx[row];
    float4 zv = *(const float4*)(z   + (size_t)row * E_DIM + lane * 4);
    float4 ev = *(const float4*)(emb + (size_t)j   * E_DIM + lane * 4);

    float4 st;
    st.x = zv.x + (ev.x - zv.x);
    st.y = zv.y + (ev.y - zv.y);
    st.z = zv.z + (ev.z - zv.z);
    st.w = zv.w + (ev.w - zv.w);
    const size_t zq0 = 1ull + (size_t)N_ROWS * N_E;
    *(float4*)(out + zq0 + (size_t)row * E_DIM + lane * 4) = st;

    double dx = (double)ev.x - zv.x, dy = (double)ev.y - zv.y;
    double dz = (double)ev.z - zv.z, dw = (double)ev.w - zv.w;
    double s = dx * dx + dy * dy + dz * dz + dw * dw;
    #pragma unroll
    for (int off = 1; off < 64; off <<= 1) s += __shfl_xor(s, off);

    if (lane == 0) {
        rowloss[row] = s;
        out[1ull + (size_t)row * N_E + j] = 1.0f;
        const size_t ix0 = 1ull + (size_t)N_ROWS * N_E + (size_t)N_ROWS * E_DIM
                         + (size_t)N_E * E_DIM;
        out[ix0 + row] = (float)j;
    }
}

// ---------- kernel 6: deterministic loss reduce ----------
__global__ __launch_bounds__(256) void k_loss(const double* __restrict__ rowloss,
                                              float* __restrict__ out) {
    __shared__ double sm[256];
    double s = 0.0;
    for (int i = threadIdx.x; i < N_ROWS; i += 256) s += rowloss[i];
    sm[threadIdx.x] = s;
    __syncthreads();
    for (int h = 128; h > 0; h >>= 1) {
        if (threadIdx.x < h) sm[threadIdx.x] += sm[threadIdx.x + h];
        __syncthreads();
    }
    if (threadIdx.x == 0)
        out[0] = (float)(sm[0] / ((double)N_ROWS * (double)E_DIM));
}

extern "C" void kernel_launch(void* const* d_in, const int* in_sizes, int n_in,
                              void* d_out, int out_size, void* d_ws, size_t ws_size,
                              hipStream_t stream) {
    const float* z   = (const float*)d_in[0];
    const float* emb = (const float*)d_in[1];
    float* out = (float*)d_out;

    char* ws = (char*)d_ws;
    float*          enf      = (float*)(ws + 0);                 // 16 KB
    float*          znf      = (float*)(ws + 16384);             // 128 KB
    int*            idx      = (int*)(ws + 147456);              // 128 KB
    int*            flagcnt  = (int*)(ws + 278528);              // 128 B
    int*            flaglist = (int*)(ws + 278656);              // 128 KB
    double*         rowloss  = (double*)(ws + 409728);           // 256 KB
    unsigned short* zhi      = (unsigned short*)(ws + 671872);   // 16 MB
    unsigned short* zlo      = (unsigned short*)(ws + 17449088); // 16 MB
    unsigned short* ehi      = (unsigned short*)(ws + 34226304); // 2 MB
    unsigned short* elo      = (unsigned short*)(ws + 36323456); // 2 MB

    // zero one-hot region + flag counter
    hipMemsetAsync(out + 1, 0, (size_t)N_ROWS * (size_t)N_E * sizeof(float), stream);
    hipMemsetAsync(flagcnt, 0, sizeof(int), stream);

    // emb passthrough chunk: exact d2d copy
    const size_t emb0 = 1ull + (size_t)N_ROWS * N_E + (size_t)N_ROWS * E_DIM;
    hipMemcpyAsync(out + emb0, emb, (size_t)N_E * E_DIM * sizeof(float),
                   hipMemcpyDeviceToDevice, stream);

    k_rownorm <<<N_E / 4, 256, 0, stream>>>(emb, enf);
    k_rownorm <<<N_ROWS / 4, 256, 0, stream>>>(z, znf);
    k_split   <<<N_ROWS / 8, 256, 0, stream>>>(z, zhi, zlo);
    k_split   <<<N_E / 8, 256, 0, stream>>>(emb, ehi, elo);
    k_screen  <<<N_ROWS / 64, 256, 0, stream>>>(zhi, zlo, ehi, elo, enf, znf,
                                                idx, flaglist, flagcnt);
    k_repair  <<<1024, 256, 0, stream>>>(z, emb, enf, znf, flagcnt, flaglist, idx);
    k_epilogue<<<N_ROWS / 4, 256, 0, stream>>>(z, emb, idx, out, rowloss);
    k_loss    <<<1, 256, 0, stream>>>(rowloss, out);
}